// Round 18
// baseline (1557.984 us; speedup 1.0000x reference)
//
#include <hip/hip_runtime.h>
#include <hip/hip_fp16.h>
#include <stdint.h>

// Bidirectional LSTM: N=1024, T=512, H=128; enc 2->128->128; dec 256->128->1.
// fp16 MFMA (fp32 accum). ws = 256 MiB:
//   bufA 128MiB: feat -> overwritten in place with relu(h_fw)   [t][n][128] fp16
//   bufB 128MiB: feat -> overwritten in place with relu(h_bw)   [t][n][128] fp16
// Round-18 LSTM: 512 blocks x 4 chains, 4-step feat batching, 2 blocks/CU.
//   r17 showed the step is latency-bound at 2 waves/SIMD (MFMA cut 25% ->
//   only 3% faster; pipe-sum fell to 78%). Fix TLP with INDEPENDENT
//   co-resident blocks (separate barriers -> true wave-level overlap, m114),
//   not intra-block tricks (r8-r14 all failed).
//   A/C row R = 4*chain + stepofs: feat = 16 MFMA / 4-step window (zero
//   M-waste); h-part via 4 pre-zeroed Z buffers (Z[j] active rows 4c+j, rest
//   permanent 0 -> +0 contributions, bit-exact) = 16/step. 20 MFMA/wave/step.
//   Lane owns ONE (chain lq, dim 16w+lr) c-state; EW = 1 value/pass.
//   Per-value FP op order identical to r7 -> absmax oracle 2.441406e-4.
// enc/dec: r16 versions (coalesced stores / amortized weights).

#define TN 512
#define NB 1024

typedef __attribute__((ext_vector_type(8))) _Float16 f16x8;
typedef __attribute__((ext_vector_type(4))) float f32x4;

#define MFMA16(a,b,c) __builtin_amdgcn_mfma_f32_16x16x32_f16(a,b,c,0,0,0)
#define RCP(x) __builtin_amdgcn_rcpf(x)

__device__ __forceinline__ f16x8 cvt_frag(const float* p){
  f32x4 a = *(const f32x4*)p;
  f32x4 b = *(const f32x4*)(p+4);
  f16x8 h;
  h[0]=(_Float16)a[0]; h[1]=(_Float16)a[1]; h[2]=(_Float16)a[2]; h[3]=(_Float16)a[3];
  h[4]=(_Float16)b[0]; h[5]=(_Float16)b[1]; h[6]=(_Float16)b[2]; h[7]=(_Float16)b[3];
  return h;
}

__device__ __forceinline__ unsigned short f2h(float f){
  return __half_as_ushort(__float2half(f));
}

// ---------------- K0: encoder -> feat fp16 [t][n][128], both copies, coalesced ----------------
__global__ __launch_bounds__(256) void enc_kernel(
    const float* __restrict__ x,  const float* __restrict__ e1w,
    const float* __restrict__ e1b,const float* __restrict__ e2w,
    const float* __restrict__ e2b,
    unsigned short* __restrict__ featA, unsigned short* __restrict__ featB)
{
  __shared__ float xs[64][2];
  __shared__ unsigned int A32[64][68];     // r1 fp16 pairs, row stride 272B
  __shared__ unsigned short A2[64][136];   // feat fp16 staging, row stride 272B
  int tid = threadIdx.x;
  long rowbase = (long)blockIdx.x * 64;  // row = t*1024 + n
  if (tid < 128){
    int i = tid >> 1, cc = tid & 1;
    long row = rowbase + i;
    int t = (int)(row >> 10), n = (int)(row & 1023);
    xs[i][cc] = x[((size_t)n * TN + t) * 2 + cc];
  }
  int w4 = tid >> 6, lane = tid & 63, lq = lane >> 4, lr = lane & 15;
  f16x8 Bf[2][4];
  float b2v[2];
  #pragma unroll
  for (int nt2 = 0; nt2 < 2; nt2++){
    int col = (w4*2 + nt2)*16 + lr;
    b2v[nt2] = e2b[col];
    #pragma unroll
    for (int ks = 0; ks < 4; ks++)
      Bf[nt2][ks] = cvt_frag(e2w + col*128 + ks*32 + lq*8);
  }
  int q = tid >> 6, dp = tid & 63;
  float w00 = e1w[4*dp], w01 = e1w[4*dp+1], w10 = e1w[4*dp+2], w11 = e1w[4*dp+3];
  float b0 = e1b[2*dp], b1 = e1b[2*dp+1];
  __syncthreads();
  #pragma unroll
  for (int rr = 0; rr < 16; rr++){
    int r = q*16 + rr;
    float x0 = xs[r][0], x1 = xs[r][1];
    float v0 = fmaxf(w00*x0 + w01*x1 + b0, 0.f);
    float v1 = fmaxf(w10*x0 + w11*x1 + b1, 0.f);
    A32[r][dp] = (unsigned int)f2h(v0) | ((unsigned int)f2h(v1) << 16);
  }
  __syncthreads();
  #pragma unroll
  for (int Mt = 0; Mt < 4; Mt++){
    f16x8 ah[4];
    #pragma unroll
    for (int ks = 0; ks < 4; ks++)
      ah[ks] = *(const f16x8*)((const unsigned short*)&A32[Mt*16+lr][0] + ks*32 + lq*8);
    f32x4 acc0 = {0.f,0.f,0.f,0.f}, acc1 = {0.f,0.f,0.f,0.f};
    #pragma unroll
    for (int ks = 0; ks < 4; ks++){
      acc0 = MFMA16(ah[ks], Bf[0][ks], acc0);
      acc1 = MFMA16(ah[ks], Bf[1][ks], acc1);
    }
    #pragma unroll
    for (int r = 0; r < 4; r++){
      int lrow = Mt*16 + lq*4 + r;
      A2[lrow][(w4*2+0)*16 + lr] = f2h(acc0[r] + b2v[0]);
      A2[lrow][(w4*2+1)*16 + lr] = f2h(acc1[r] + b2v[1]);
    }
  }
  __syncthreads();
  #pragma unroll
  for (int it = 0; it < 4; it++){
    int idx = it*256 + tid;            // 0..1023
    int row = idx >> 4, qq = idx & 15;
    uint4 v = *(const uint4*)&A2[row][qq*8];
    *(uint4*)(featA + ((size_t)(rowbase + row))*128 + qq*8) = v;
    *(uint4*)(featB + ((size_t)(rowbase + row))*128 + qq*8) = v;
  }
}

// ---------------- K1: persistent bidirectional LSTM (4-step batch, 2 blocks/CU) ----------------
// 512 blocks x 512 thr; block b: dir=b&1, chains n0..n0+3 (n0=(b>>1)*4).
// Wave w: gates {i,f,g,o} at dims [16w,16w+16). A/C row R = 4*chain + so.
// Lane (lq,lr) owns chain lq, dim 16w+lr; acc[G][r] = gate G, window step r.
// Z[j]: h of step-class j-1 in rows 4c+j, other rows permanent 0.
#define HPASS(J) do { \
    f16x8 ah[4]; \
    _Pragma("unroll") \
    for (int ks = 0; ks < 4; ks++) ah[ks] = *(const f16x8*)&Z[J][lr][ks*32 + lq*8]; \
    _Pragma("unroll") \
    for (int ks = 0; ks < 4; ks++){ \
      _Pragma("unroll") \
      for (int G = 0; G < 4; G++) acc[G] = MFMA16(ah[ks], wh[G][ks], acc[G]); \
    } \
    { \
      float iv = acc[0][J], fv = acc[1][J], gv = acc[2][J], ov = acc[3][J]; \
      float si = RCP(1.f + __expf(-iv)); \
      float sf = RCP(1.f + __expf(-fv)); \
      float so = RCP(1.f + __expf(-ov)); \
      float tg = 1.f - 2.f*RCP(__expf(2.f*gv) + 1.f); \
      cst = sf*cst + si*tg; \
      float tc = 1.f - 2.f*RCP(__expf(2.f*cst) + 1.f); \
      float hv = so*tc; \
      unsigned short hh = f2h(hv); \
      Z[((J)+1)&3][4*lq + (((J)+1)&3)][w*16 + lr] = hh; \
      *op = (hv > 0.f) ? hh : (unsigned short)0; \
      op += dstep; \
    } \
    __syncthreads(); \
  } while(0)

#define LSTM_WINDOW(PFC, PFN) do { \
    _Pragma("unroll") \
    for (int ks = 0; ks < 4; ks++) PFN[ks] = *(const uint4*)(fpp + ks*32); \
    fpp += 4*dstep; \
    f32x4 acc[4]; \
    _Pragma("unroll") \
    for (int G = 0; G < 4; G++) acc[G] = MFMA16(*(const f16x8*)&PFC[0], wf[G][0], zero4); \
    _Pragma("unroll") \
    for (int ks = 1; ks < 4; ks++){ \
      _Pragma("unroll") \
      for (int G = 0; G < 4; G++) acc[G] = MFMA16(*(const f16x8*)&PFC[ks], wf[G][ks], acc[G]); \
    } \
    HPASS(0); \
    HPASS(1); \
    HPASS(2); \
    HPASS(3); \
  } while(0)

__global__ __launch_bounds__(512, 4) void lstm_kernel(
    unsigned short* bufA, unsigned short* bufB,
    const float* __restrict__ wih, const float* __restrict__ whh)
{
  // Z[j] active rows 4c+j only; all other rows zeroed once and never written.
  __shared__ __align__(16) unsigned short Z[4][16][136];   // 17408 B
  int tid = threadIdx.x, b = blockIdx.x;
  int dir = b & 1, n0 = (b >> 1) << 2;
  int w = tid >> 6, lane = tid & 63, lq = lane >> 4, lr = lane & 15;
  unsigned short* buf = dir ? bufB : bufA;

  // resident fp16 weight fragments: wf = w_ih (feat), wh = w_hh (h)
  f16x8 wf[4][4], wh[4][4];
  #pragma unroll
  for (int G = 0; G < 4; G++){
    int gate = G*128 + w*16 + lr;
    #pragma unroll
    for (int ks = 0; ks < 4; ks++){
      wf[G][ks] = cvt_frag(wih + (size_t)gate*128 + ks*32 + lq*8);
      wh[G][ks] = cvt_frag(whh + (size_t)gate*128 + ks*32 + lq*8);
    }
  }

  for (int i = tid; i < 4352; i += 512) ((unsigned int*)Z)[i] = 0u;

  float cst = 0.f;
  const f32x4 zero4 = {0.f, 0.f, 0.f, 0.f};
  int t0 = dir ? (TN-1) : 0;
  long dstep = dir ? -(long)(NB*128) : (long)(NB*128);

  // feat A-row lr = (chain lr>>2, step-ofs lr&3); window stride = 4 steps
  const unsigned short* fpp = buf + ((size_t)t0*NB + n0 + (lr >> 2))*128
                            + (long)(lr & 3)*dstep + lq*8;
  uint4 pfA[4], pfB[4];
  #pragma unroll
  for (int ks = 0; ks < 4; ks++) pfA[ks] = *(const uint4*)(fpp + ks*32);   // window 0
  fpp += 4*dstep;
  // Final-window prefetch over-reads reach t0 +/- (512..515): fw lands in
  // bufB's first ~1MB, bw in bufA's last ~1MB — inside ws; values dead.

  // output pointer: (chain lq, dim 16w+lr); advances dstep per pass
  unsigned short* op = buf + ((size_t)t0*NB + n0 + lq)*128 + (w*16 + lr);
  __syncthreads();

  for (int wd = 0; wd < 64; wd++){
    LSTM_WINDOW(pfA, pfB);
    LSTM_WINDOW(pfB, pfA);
  }
}

// ---------------- K2: decoder (fp16 MFMA, K=256); 2048 blocks x 256 rows ----------------
__global__ __launch_bounds__(256) void dec_kernel(
    const unsigned short* __restrict__ hfw, const unsigned short* __restrict__ hbw,
    const float* __restrict__ d1w, const float* __restrict__ d1b,
    const float* __restrict__ d2w, const float* __restrict__ d2b,
    float* __restrict__ out)
{
  __shared__ unsigned short A[64][264];  // [hfw||hbw], row stride 528B
  __shared__ float partial[4][64];
  int tid = threadIdx.x;
  int w4 = tid >> 6, lane = tid & 63, lq = lane >> 4, lr = lane & 15;
  f16x8 Bf[2][8];
  float b1v[2], w2v[2];
  #pragma unroll
  for (int nt2 = 0; nt2 < 2; nt2++){
    int col = (w4*2 + nt2)*16 + lr;
    b1v[nt2] = d1b[col];
    w2v[nt2] = d2w[col];
    #pragma unroll
    for (int ks = 0; ks < 8; ks++)
      Bf[nt2][ks] = cvt_frag(d1w + col*256 + ks*32 + lq*8);
  }
  float b2s = d2b[0];

  for (int ch = 0; ch < 4; ch++){
    long rowbase = (long)blockIdx.x * 256 + ch * 64;
    #pragma unroll
    for (int u = 0; u < 8; u++){
      int chunk = u*256 + tid;             // 0..2047
      int row = chunk >> 5, seg = chunk & 31;
      const unsigned short* src = (seg < 16)
          ? (hfw + ((size_t)(rowbase + row))*128 + seg*8)
          : (hbw + ((size_t)(rowbase + row))*128 + (seg-16)*8);
      *(uint4*)&A[row][seg*8] = *(const uint4*)src;
    }
    __syncthreads();
    #pragma unroll
    for (int Mt = 0; Mt < 4; Mt++){
      f16x8 ah[8];
      #pragma unroll
      for (int ks = 0; ks < 8; ks++)
        ah[ks] = *(const f16x8*)&A[Mt*16+lr][ks*32 + lq*8];
      f32x4 acc0 = {0.f,0.f,0.f,0.f}, acc1 = {0.f,0.f,0.f,0.f};
      #pragma unroll
      for (int ks = 0; ks < 8; ks++){
        acc0 = MFMA16(ah[ks], Bf[0][ks], acc0);
        acc1 = MFMA16(ah[ks], Bf[1][ks], acc1);
      }
      #pragma unroll
      for (int r = 0; r < 4; r++){
        float p = fmaxf(acc0[r] + b1v[0], 0.f) * w2v[0]
                + fmaxf(acc1[r] + b1v[1], 0.f) * w2v[1];
        p += __shfl_xor(p, 1);
        p += __shfl_xor(p, 2);
        p += __shfl_xor(p, 4);
        p += __shfl_xor(p, 8);
        if (lr == 0) partial[w4][Mt*16 + lq*4 + r] = p;
      }
    }
    __syncthreads();
    if (tid < 64){
      long row = rowbase + tid;
      int t = (int)(row >> 10), n = (int)(row & 1023);
      out[(size_t)n*TN + t] = partial[0][tid] + partial[1][tid]
                            + partial[2][tid] + partial[3][tid] + b2s;
    }
  }
}

extern "C" void kernel_launch(void* const* d_in, const int* in_sizes, int n_in,
                              void* d_out, int out_size, void* d_ws, size_t ws_size,
                              hipStream_t stream)
{
  const float* x   = (const float*)d_in[0];
  const float* e1w = (const float*)d_in[1];
  const float* e1b = (const float*)d_in[2];
  const float* e2w = (const float*)d_in[3];
  const float* e2b = (const float*)d_in[4];
  const float* wih = (const float*)d_in[5];
  const float* whh = (const float*)d_in[6];
  const float* d1w = (const float*)d_in[7];
  const float* d1b = (const float*)d_in[8];
  const float* d2w = (const float*)d_in[9];
  const float* d2b = (const float*)d_in[10];
  float* out = (float*)d_out;

  if (ws_size < ((size_t)256 << 20)) return;   // ws guard (rounds 1-2 crashed on ws overflow)

  char* ws = (char*)d_ws;
  unsigned short* bufA = (unsigned short*)ws;                            // 128 MiB
  unsigned short* bufB = (unsigned short*)(ws + (((size_t)128) << 20));  // 128 MiB

  hipLaunchKernelGGL(enc_kernel, dim3(8192), dim3(256), 0, stream, x, e1w, e1b, e2w, e2b, bufA, bufB);
  hipLaunchKernelGGL(lstm_kernel, dim3(512), dim3(512), 0, stream, bufA, bufB, wih, whh);
  hipLaunchKernelGGL(dec_kernel, dim3(2048), dim3(256), 0, stream, bufA, bufB, d1w, d1b, d2w, d2b, out);
}

// Round 19
// 620.364 us; speedup vs baseline: 2.5114x; 2.5114x over previous
//
#include <hip/hip_runtime.h>
#include <hip/hip_fp16.h>
#include <stdint.h>

// Bidirectional LSTM: N=1024, T=512, H=128; enc 2->128->128; dec 256->128->1.
// fp16 MFMA (fp32 accum). ws = 256 MiB:
//   bufA 128MiB: feat -> overwritten in place with relu(h_fw)   [t][n][128] fp16
//   bufB 128MiB: feat -> overwritten in place with relu(h_bw)   [t][n][128] fp16
// Round-19: RESTORE best (r17 = 619us). r18's occupancy push proved the
// structural law: weight residency costs ~192 combined regs/wave -> max 2
// waves/SIMD; any launch_bounds beyond that evicts weights (VGPR=64, 4GB
// refetch, 3x slower). LSTM: 256 blocks x 512 thr, 8 chains, 2-step feat
// batching (24 MFMA/wave/step), pre-zeroed Z-buffer trick (bit-exact).
// enc: LDS repack + coalesced uint4 dual-copy stores (write-bound floor).
// dec: 2048 blocks x 256 rows, weights converted once per block (read-bound).
// absmax oracle 2.441406e-4 (exact, verified r17).

#define TN 512
#define NB 1024

typedef __attribute__((ext_vector_type(8))) _Float16 f16x8;
typedef __attribute__((ext_vector_type(4))) float f32x4;

#define MFMA16(a,b,c) __builtin_amdgcn_mfma_f32_16x16x32_f16(a,b,c,0,0,0)
#define RCP(x) __builtin_amdgcn_rcpf(x)

__device__ __forceinline__ f16x8 cvt_frag(const float* p){
  f32x4 a = *(const f32x4*)p;
  f32x4 b = *(const f32x4*)(p+4);
  f16x8 h;
  h[0]=(_Float16)a[0]; h[1]=(_Float16)a[1]; h[2]=(_Float16)a[2]; h[3]=(_Float16)a[3];
  h[4]=(_Float16)b[0]; h[5]=(_Float16)b[1]; h[6]=(_Float16)b[2]; h[7]=(_Float16)b[3];
  return h;
}

__device__ __forceinline__ unsigned short f2h(float f){
  return __half_as_ushort(__float2half(f));
}

// ---------------- K0: encoder -> feat fp16 [t][n][128], both copies, coalesced ----------------
__global__ __launch_bounds__(256) void enc_kernel(
    const float* __restrict__ x,  const float* __restrict__ e1w,
    const float* __restrict__ e1b,const float* __restrict__ e2w,
    const float* __restrict__ e2b,
    unsigned short* __restrict__ featA, unsigned short* __restrict__ featB)
{
  __shared__ float xs[64][2];
  __shared__ unsigned int A32[64][68];     // r1 fp16 pairs, row stride 272B
  __shared__ unsigned short A2[64][136];   // feat fp16 staging, row stride 272B
  int tid = threadIdx.x;
  long rowbase = (long)blockIdx.x * 64;  // row = t*1024 + n
  if (tid < 128){
    int i = tid >> 1, cc = tid & 1;
    long row = rowbase + i;
    int t = (int)(row >> 10), n = (int)(row & 1023);
    xs[i][cc] = x[((size_t)n * TN + t) * 2 + cc];
  }
  int w4 = tid >> 6, lane = tid & 63, lq = lane >> 4, lr = lane & 15;
  f16x8 Bf[2][4];
  float b2v[2];
  #pragma unroll
  for (int nt2 = 0; nt2 < 2; nt2++){
    int col = (w4*2 + nt2)*16 + lr;
    b2v[nt2] = e2b[col];
    #pragma unroll
    for (int ks = 0; ks < 4; ks++)
      Bf[nt2][ks] = cvt_frag(e2w + col*128 + ks*32 + lq*8);
  }
  int q = tid >> 6, dp = tid & 63;
  float w00 = e1w[4*dp], w01 = e1w[4*dp+1], w10 = e1w[4*dp+2], w11 = e1w[4*dp+3];
  float b0 = e1b[2*dp], b1 = e1b[2*dp+1];
  __syncthreads();
  #pragma unroll
  for (int rr = 0; rr < 16; rr++){
    int r = q*16 + rr;
    float x0 = xs[r][0], x1 = xs[r][1];
    float v0 = fmaxf(w00*x0 + w01*x1 + b0, 0.f);
    float v1 = fmaxf(w10*x0 + w11*x1 + b1, 0.f);
    A32[r][dp] = (unsigned int)f2h(v0) | ((unsigned int)f2h(v1) << 16);
  }
  __syncthreads();
  #pragma unroll
  for (int Mt = 0; Mt < 4; Mt++){
    f16x8 ah[4];
    #pragma unroll
    for (int ks = 0; ks < 4; ks++)
      ah[ks] = *(const f16x8*)((const unsigned short*)&A32[Mt*16+lr][0] + ks*32 + lq*8);
    f32x4 acc0 = {0.f,0.f,0.f,0.f}, acc1 = {0.f,0.f,0.f,0.f};
    #pragma unroll
    for (int ks = 0; ks < 4; ks++){
      acc0 = MFMA16(ah[ks], Bf[0][ks], acc0);
      acc1 = MFMA16(ah[ks], Bf[1][ks], acc1);
    }
    #pragma unroll
    for (int r = 0; r < 4; r++){
      int lrow = Mt*16 + lq*4 + r;
      A2[lrow][(w4*2+0)*16 + lr] = f2h(acc0[r] + b2v[0]);
      A2[lrow][(w4*2+1)*16 + lr] = f2h(acc1[r] + b2v[1]);
    }
  }
  __syncthreads();
  #pragma unroll
  for (int it = 0; it < 4; it++){
    int idx = it*256 + tid;            // 0..1023
    int row = idx >> 4, qq = idx & 15;
    uint4 v = *(const uint4*)&A2[row][qq*8];
    *(uint4*)(featA + ((size_t)(rowbase + row))*128 + qq*8) = v;
    *(uint4*)(featB + ((size_t)(rowbase + row))*128 + qq*8) = v;
  }
}

// ---------------- K1: persistent bidirectional LSTM (2-step feat batching) ----------------
// 256 blocks x 512 thr; block b: dir=b>>7, chains n0..n0+7.
// A/C row R = 2*chain + so. Lane owns C rows lq*4+r: r={0,2} = step-even for
// chains {2lq, 2lq+1}; r={1,3} = step-odd. Wave w: gates {i,f,g,o} at dims
// [16w,16w+16). Elementwise per value identical to r7.
#define LSTM_EW(RA, RB, ZW, RO) do { \
    float iv0=acc[0][RA], fv0=acc[1][RA], gv0=acc[2][RA], ov0=acc[3][RA]; \
    float si0 = RCP(1.f + __expf(-iv0)); \
    float sf0 = RCP(1.f + __expf(-fv0)); \
    float so0 = RCP(1.f + __expf(-ov0)); \
    float tg0 = 1.f - 2.f*RCP(__expf(2.f*gv0) + 1.f); \
    c[0] = sf0*c[0] + si0*tg0; \
    float tc0 = 1.f - 2.f*RCP(__expf(2.f*c[0]) + 1.f); \
    float hv0 = so0*tc0; \
    float iv1=acc[0][RB], fv1=acc[1][RB], gv1=acc[2][RB], ov1=acc[3][RB]; \
    float si1 = RCP(1.f + __expf(-iv1)); \
    float sf1 = RCP(1.f + __expf(-fv1)); \
    float so1 = RCP(1.f + __expf(-ov1)); \
    float tg1 = 1.f - 2.f*RCP(__expf(2.f*gv1) + 1.f); \
    c[1] = sf1*c[1] + si1*tg1; \
    float tc1 = 1.f - 2.f*RCP(__expf(2.f*c[1]) + 1.f); \
    float hv1 = so1*tc1; \
    unsigned short hh0 = f2h(hv0), hh1 = f2h(hv1); \
    ZW[4*lq + (RO)][w*16 + lr]     = hh0; \
    ZW[4*lq + 2 + (RO)][w*16 + lr] = hh1; \
    op[0]   = (hv0 > 0.f) ? hh0 : (unsigned short)0; \
    op[128] = (hv1 > 0.f) ? hh1 : (unsigned short)0; \
    op += dstep; \
  } while(0)

#define LSTM_WINDOW(PFC, PFN) do { \
    _Pragma("unroll") \
    for (int ks = 0; ks < 4; ks++) PFN[ks] = *(const uint4*)(fpp + ks*32); \
    fpp += 2*dstep; \
    f32x4 acc[4]; \
    _Pragma("unroll") \
    for (int G = 0; G < 4; G++) acc[G] = MFMA16(*(const f16x8*)&PFC[0], wf[G][0], zero4); \
    _Pragma("unroll") \
    for (int ks = 1; ks < 4; ks++){ \
      _Pragma("unroll") \
      for (int G = 0; G < 4; G++) acc[G] = MFMA16(*(const f16x8*)&PFC[ks], wf[G][ks], acc[G]); \
    } \
    { /* pass 1: h(s-1) from Z1 (odd rows are permanent zeros) */ \
      f16x8 ah[4]; \
      _Pragma("unroll") \
      for (int ks = 0; ks < 4; ks++) ah[ks] = *(const f16x8*)&Z[0][lr][ks*32 + lq*8]; \
      _Pragma("unroll") \
      for (int ks = 0; ks < 4; ks++){ \
        _Pragma("unroll") \
        for (int G = 0; G < 4; G++) acc[G] = MFMA16(ah[ks], wh[G][ks], acc[G]); \
      } \
    } \
    LSTM_EW(0, 2, Z[1], 1);   /* even step: rows 4lq+1, 4lq+3 of Z2 */ \
    __syncthreads();          /* A: Z2 h-rows visible; Z1 reads done */ \
    { /* pass 2: h(s) from Z2 (even rows are permanent zeros) */ \
      f16x8 ah[4]; \
      _Pragma("unroll") \
      for (int ks = 0; ks < 4; ks++) ah[ks] = *(const f16x8*)&Z[1][lr][ks*32 + lq*8]; \
      _Pragma("unroll") \
      for (int ks = 0; ks < 4; ks++){ \
        _Pragma("unroll") \
        for (int G = 0; G < 4; G++) acc[G] = MFMA16(ah[ks], wh[G][ks], acc[G]); \
      } \
    } \
    LSTM_EW(1, 3, Z[0], 0);   /* odd step: rows 4lq, 4lq+2 of Z1 */ \
    __syncthreads();          /* B: Z1 h-rows visible; Z2 reads done */ \
  } while(0)

__global__ __launch_bounds__(512, 2) void lstm_kernel(
    unsigned short* bufA, unsigned short* bufB,
    const float* __restrict__ wih, const float* __restrict__ whh)
{
  // Z[0]=Z1: h in even rows (written by odd-step EW), odd rows always 0.
  // Z[1]=Z2: h in odd rows (written by even-step EW), even rows always 0.
  __shared__ __align__(16) unsigned short Z[2][16][136];   // 8704 B
  int tid = threadIdx.x, b = blockIdx.x;
  int dir = b >> 7, n0 = (b & 127) << 3;
  int w = tid >> 6, lane = tid & 63, lq = lane >> 4, lr = lane & 15;
  unsigned short* buf = dir ? bufB : bufA;

  // resident fp16 weight fragments: wf = w_ih (feat part), wh = w_hh (h part)
  f16x8 wf[4][4], wh[4][4];
  #pragma unroll
  for (int G = 0; G < 4; G++){
    int gate = G*128 + w*16 + lr;
    #pragma unroll
    for (int ks = 0; ks < 4; ks++){
      wf[G][ks] = cvt_frag(wih + (size_t)gate*128 + ks*32 + lq*8);
      wh[G][ks] = cvt_frag(whh + (size_t)gate*128 + ks*32 + lq*8);
    }
  }

  for (int i = tid; i < 2176; i += 512) ((unsigned int*)Z)[i] = 0u;

  float c[2] = {0.f, 0.f};
  const f32x4 zero4 = {0.f, 0.f, 0.f, 0.f};
  int t0 = dir ? (TN-1) : 0;
  long dstep = dir ? -(long)(NB*128) : (long)(NB*128);

  // feat A-row lr = (chain lr>>1, step-ofs lr&1); window stride = 2 steps
  const unsigned short* fpp = buf + ((size_t)t0*NB + n0 + (lr >> 1))*128
                            + (long)(lr & 1)*dstep + lq*8;
  uint4 pfA[4], pfB[4];
  #pragma unroll
  for (int ks = 0; ks < 4; ks++) pfA[ks] = *(const uint4*)(fpp + ks*32);   // window 0
  fpp += 2*dstep;
  // Boundary over-reads (last window prefetches t0 +/- 512..513) stay inside
  // ws: fw lands at bufB's start rows, bw at bufA's end rows; values dead.

  // output pointer: chains 2lq (+1 via offset 128), dim w*16+lr; +=dstep per EW
  unsigned short* op = buf + ((size_t)t0*NB + n0 + lq*2)*128 + (w*16 + lr);
  __syncthreads();

  for (int wd = 0; wd < 128; wd++){
    LSTM_WINDOW(pfA, pfB);
    LSTM_WINDOW(pfB, pfA);
  }
}

// ---------------- K2: decoder (fp16 MFMA, K=256); 2048 blocks x 256 rows ----------------
__global__ __launch_bounds__(256) void dec_kernel(
    const unsigned short* __restrict__ hfw, const unsigned short* __restrict__ hbw,
    const float* __restrict__ d1w, const float* __restrict__ d1b,
    const float* __restrict__ d2w, const float* __restrict__ d2b,
    float* __restrict__ out)
{
  __shared__ unsigned short A[64][264];  // [hfw||hbw], row stride 528B
  __shared__ float partial[4][64];
  int tid = threadIdx.x;
  int w4 = tid >> 6, lane = tid & 63, lq = lane >> 4, lr = lane & 15;
  f16x8 Bf[2][8];
  float b1v[2], w2v[2];
  #pragma unroll
  for (int nt2 = 0; nt2 < 2; nt2++){
    int col = (w4*2 + nt2)*16 + lr;
    b1v[nt2] = d1b[col];
    w2v[nt2] = d2w[col];
    #pragma unroll
    for (int ks = 0; ks < 8; ks++)
      Bf[nt2][ks] = cvt_frag(d1w + col*256 + ks*32 + lq*8);
  }
  float b2s = d2b[0];

  for (int ch = 0; ch < 4; ch++){
    long rowbase = (long)blockIdx.x * 256 + ch * 64;
    #pragma unroll
    for (int u = 0; u < 8; u++){
      int chunk = u*256 + tid;             // 0..2047
      int row = chunk >> 5, seg = chunk & 31;
      const unsigned short* src = (seg < 16)
          ? (hfw + ((size_t)(rowbase + row))*128 + seg*8)
          : (hbw + ((size_t)(rowbase + row))*128 + (seg-16)*8);
      *(uint4*)&A[row][seg*8] = *(const uint4*)src;
    }
    __syncthreads();
    #pragma unroll
    for (int Mt = 0; Mt < 4; Mt++){
      f16x8 ah[8];
      #pragma unroll
      for (int ks = 0; ks < 8; ks++)
        ah[ks] = *(const f16x8*)&A[Mt*16+lr][ks*32 + lq*8];
      f32x4 acc0 = {0.f,0.f,0.f,0.f}, acc1 = {0.f,0.f,0.f,0.f};
      #pragma unroll
      for (int ks = 0; ks < 8; ks++){
        acc0 = MFMA16(ah[ks], Bf[0][ks], acc0);
        acc1 = MFMA16(ah[ks], Bf[1][ks], acc1);
      }
      #pragma unroll
      for (int r = 0; r < 4; r++){
        float p = fmaxf(acc0[r] + b1v[0], 0.f) * w2v[0]
                + fmaxf(acc1[r] + b1v[1], 0.f) * w2v[1];
        p += __shfl_xor(p, 1);
        p += __shfl_xor(p, 2);
        p += __shfl_xor(p, 4);
        p += __shfl_xor(p, 8);
        if (lr == 0) partial[w4][Mt*16 + lq*4 + r] = p;
      }
    }
    __syncthreads();
    if (tid < 64){
      long row = rowbase + tid;
      int t = (int)(row >> 10), n = (int)(row & 1023);
      out[(size_t)n*TN + t] = partial[0][tid] + partial[1][tid]
                            + partial[2][tid] + partial[3][tid] + b2s;
    }
  }
}

extern "C" void kernel_launch(void* const* d_in, const int* in_sizes, int n_in,
                              void* d_out, int out_size, void* d_ws, size_t ws_size,
                              hipStream_t stream)
{
  const float* x   = (const float*)d_in[0];
  const float* e1w = (const float*)d_in[1];
  const float* e1b = (const float*)d_in[2];
  const float* e2w = (const float*)d_in[3];
  const float* e2b = (const float*)d_in[4];
  const float* wih = (const float*)d_in[5];
  const float* whh = (const float*)d_in[6];
  const float* d1w = (const float*)d_in[7];
  const float* d1b = (const float*)d_in[8];
  const float* d2w = (const float*)d_in[9];
  const float* d2b = (const float*)d_in[10];
  float* out = (float*)d_out;

  if (ws_size < ((size_t)256 << 20)) return;   // ws guard (rounds 1-2 crashed on ws overflow)

  char* ws = (char*)d_ws;
  unsigned short* bufA = (unsigned short*)ws;                            // 128 MiB
  unsigned short* bufB = (unsigned short*)(ws + (((size_t)128) << 20));  // 128 MiB

  hipLaunchKernelGGL(enc_kernel, dim3(8192), dim3(256), 0, stream, x, e1w, e1b, e2w, e2b, bufA, bufB);
  hipLaunchKernelGGL(lstm_kernel, dim3(256), dim3(512), 0, stream, bufA, bufB, wih, whh);
  hipLaunchKernelGGL(dec_kernel, dim3(2048), dim3(256), 0, stream, bufA, bufB, d1w, d1b, d2w, d2b, out);
}